// Round 2
// baseline (701.711 us; speedup 1.0000x reference)
//
#include <hip/hip_runtime.h>

// HDC token encoder: out[b,i,d] = item_memory[token_ids[b,i]][(d - i) mod D] * 0.01f
// B=8, S=2048, V=256, D=10000. Every +/-1 row has L2 norm exactly 100, so the
// normalize is a constant scale by 0.01f (bit-exact vs reference, verified R0).
//
// R1: stage the source row in LDS (float4 loads, pre-scaled), then emit with
// stride-1 conflict-free LDS reads + coalesced nontemporal scalar stores.

#define B_ 8
#define S_ 2048
#define D_ 10000

__global__ __launch_bounds__(256) void hdc_encode(
    const int* __restrict__ token_ids,
    const float* __restrict__ item_memory,
    float* __restrict__ out)
{
    __shared__ float lds[D_];            // 40000 B -> 4 blocks/CU (160 KiB LDS)

    const int row = blockIdx.x;          // 0 .. B*S-1
    const int i   = row & (S_ - 1);      // shift amount (S is a power of two)
    const int tok = token_ids[row];

    const float*  __restrict__ src  = item_memory + (size_t)tok * D_;
    const float4* __restrict__ src4 = reinterpret_cast<const float4*>(src); // row base 40000B-strided, 16B aligned

    // Stage row into LDS, pre-scaled. 2500 float4 chunks / 256 threads.
    for (int c = threadIdx.x; c < D_ / 4; c += 256) {
        float4 v = src4[c];
        lds[4 * c + 0] = v.x * 0.01f;
        lds[4 * c + 1] = v.y * 0.01f;
        lds[4 * c + 2] = v.z * 0.01f;
        lds[4 * c + 3] = v.w * 0.01f;
    }
    __syncthreads();

    float* __restrict__ dst = out + (size_t)row * D_;

    // dst[d] = lds[(d - i) mod D]. d-i in [-2047, 9999] so a single +D wrap
    // suffices. Consecutive lanes read consecutive LDS dwords (2-way = free)
    // and store 256B contiguous per wave.
    for (int d = threadIdx.x; d < D_; d += 256) {
        int s = d - i;
        if (s < 0) s += D_;
        __builtin_nontemporal_store(lds[s], dst + d);
    }
}

extern "C" void kernel_launch(void* const* d_in, const int* in_sizes, int n_in,
                              void* d_out, int out_size, void* d_ws, size_t ws_size,
                              hipStream_t stream)
{
    const int*   token_ids   = (const int*)d_in[0];
    const float* item_memory = (const float*)d_in[1];
    float*       out         = (float*)d_out;

    hdc_encode<<<dim3(B_ * S_), dim3(256), 0, stream>>>(token_ids, item_memory, out);
}

// Round 4
// 680.454 us; speedup vs baseline: 1.0312x; 1.0312x over previous
//
#include <hip/hip_runtime.h>

// HDC token encoder: out[b,i,d] = item_memory[token_ids[b,i]][(d - i) mod D] * 0.01f
// B=8, S=2048, V=256, D=10000. Every +/-1 row has L2 norm exactly 100, so the
// normalize is a constant scale by 0.01f (bit-exact vs reference, verified R0).
//
// R4 (= R3 fixed): no LDS. float4 on both sides. Source offset s = (4c - i) mod D
// has a constant phase (s mod 4) per row, so we issue 4B-aligned
// global_load_dwordx4 (gfx9+ allows unaligned vector loads). Only the one chunk
// per row whose 16B window crosses the row end takes the scalar wrap path.
// Nontemporal stores keep L2 reserved for the 10 MB item_memory working set.
// Note: __builtin_nontemporal_store needs clang ext-vector types, not HIP float4.

#define B_ 8
#define S_ 2048
#define D_ 10000

typedef float vf4  __attribute__((ext_vector_type(4)));              // 16B aligned
typedef float vf4u __attribute__((ext_vector_type(4), aligned(4)));  // 4B aligned

__global__ __launch_bounds__(256) void hdc_encode(
    const int* __restrict__ token_ids,
    const float* __restrict__ item_memory,
    float* __restrict__ out)
{
    const int row = blockIdx.x;          // 0 .. B*S-1
    const int i   = row & (S_ - 1);      // shift amount (S is a power of two)
    const int tok = token_ids[row];

    const float* __restrict__ src  = item_memory + (size_t)tok * D_;
    vf4*         __restrict__ dst4 = reinterpret_cast<vf4*>(out + (size_t)row * D_);

    // s for chunk c: (4c - i) mod D; starts at 4*tid - i, advances by 1024.
    int s = 4 * (int)threadIdx.x - i;
    if (s < 0) s += D_;

    #pragma unroll 2
    for (int c = threadIdx.x; c < D_ / 4; c += 256) {
        vf4 v;
        if (s <= D_ - 4) {
            v = *reinterpret_cast<const vf4u*>(src + s);   // 4B-aligned dwordx4
        } else {
            int s1 = s + 1; if (s1 >= D_) s1 -= D_;
            int s2 = s + 2; if (s2 >= D_) s2 -= D_;
            int s3 = s + 3; if (s3 >= D_) s3 -= D_;
            v.x = src[s]; v.y = src[s1]; v.z = src[s2]; v.w = src[s3];
        }
        v *= 0.01f;
        __builtin_nontemporal_store(v, dst4 + c);

        s += 1024;                        // 4 * 256
        if (s >= D_) s -= D_;
    }
}

extern "C" void kernel_launch(void* const* d_in, const int* in_sizes, int n_in,
                              void* d_out, int out_size, void* d_ws, size_t ws_size,
                              hipStream_t stream)
{
    const int*   token_ids   = (const int*)d_in[0];
    const float* item_memory = (const float*)d_in[1];
    float*       out         = (float*)d_out;

    hdc_encode<<<dim3(B_ * S_), dim3(256), 0, stream>>>(token_ids, item_memory, out);
}

// Round 5
// 675.824 us; speedup vs baseline: 1.0383x; 1.0069x over previous
//
#include <hip/hip_runtime.h>

// HDC token encoder: out[b,i,d] = item_memory[token_ids[b,i]][(d - i) mod D] * 0.01f
// B=8, S=2048, V=256, D=10000. Every +/-1 row has L2 norm exactly 100, so the
// normalize is a constant scale by 0.01f (bit-exact vs reference, verified R0).
//
// R5: two-phase emit to break vmcnt FIFO coupling. gfx9 loads and stores share
// vmcnt and retire FIFO, so "load; wait; store" loops make every load-wait
// drain the previous store (wave advances at store-retire latency). Here each
// thread issues ALL 10 independent gather loads first, waits once, then fires
// 10 stores that are never waited on — matching the fill kernel's
// fire-and-forget store stream (6.2 TB/s at 10% occupancy).

#define B_ 8
#define S_ 2048
#define D_ 10000
#define NCH 10                           // ceil(2500 chunks / 256 threads)

typedef float vf4  __attribute__((ext_vector_type(4)));              // 16B aligned
typedef float vf4u __attribute__((ext_vector_type(4), aligned(4)));  // 4B aligned

__global__ __launch_bounds__(256) void hdc_encode(
    const int* __restrict__ token_ids,
    const float* __restrict__ item_memory,
    float* __restrict__ out)
{
    const int row = blockIdx.x;          // 0 .. B*S-1
    const int i   = row & (S_ - 1);      // shift amount (S is a power of two)
    const int tok = token_ids[row];      // block-uniform -> scalar load

    const float* __restrict__ src = item_memory + (size_t)tok * D_;
    float*       __restrict__ dst = out + (size_t)row * D_;

    const int tid = threadIdx.x;
    // chunks c = tid + 256*j, j in [0, nj); 2500 = 9*256 + 196
    const int nj = (tid < 2500 - 9 * 256) ? NCH : NCH - 1;

    // Phase 1: gather all chunks into registers. s_j = (4*tid - i + 1024*j) mod D.
    // Per thread at most ONE chunk crosses the row end (min circular gap of the
    // 10 offsets is 784 > 3), so the scalar wrap path runs once at most.
    vf4 v[NCH];
    int s = 4 * tid - i;
    if (s < 0) s += D_;
    #pragma unroll
    for (int j = 0; j < NCH; ++j) {
        if (j < nj) {
            if (s <= D_ - 4) {
                v[j] = *reinterpret_cast<const vf4u*>(src + s);  // 4B-aligned dwordx4
            } else {
                int s1 = s + 1; if (s1 >= D_) s1 -= D_;
                int s2 = s + 2; if (s2 >= D_) s2 -= D_;
                int s3 = s + 3; if (s3 >= D_) s3 -= D_;
                v[j].x = src[s]; v[j].y = src[s1]; v[j].z = src[s2]; v[j].w = src[s3];
            }
        }
        s += 1024;                        // 4 * 256
        if (s >= D_) s -= D_;
    }

    // Phase 2: fire-and-forget store stream (contiguous 1KB per wave-instr).
    vf4* __restrict__ dst4 = reinterpret_cast<vf4*>(dst);
    #pragma unroll
    for (int j = 0; j < NCH; ++j) {
        if (j < nj) {
            __builtin_nontemporal_store(v[j] * 0.01f, dst4 + tid + 256 * j);
        }
    }
}

extern "C" void kernel_launch(void* const* d_in, const int* in_sizes, int n_in,
                              void* d_out, int out_size, void* d_ws, size_t ws_size,
                              hipStream_t stream)
{
    const int*   token_ids   = (const int*)d_in[0];
    const float* item_memory = (const float*)d_in[1];
    float*       out         = (float*)d_out;

    hdc_encode<<<dim3(B_ * S_), dim3(256), 0, stream>>>(token_ids, item_memory, out);
}